// Round 16
// baseline (238.119 us; speedup 1.0000x reference)
//
#include <hip/hip_runtime.h>
#include <cstddef>

// Problem constants
#define B_   8
#define C4_  256
#define C5_  512
#define OC_  256
#define FR_  128
#define H_   64
#define W_   64
#define HW_  4096

typedef unsigned short u16;
typedef __bf16 bf16x8 __attribute__((ext_vector_type(8)));
typedef float floatx16 __attribute__((ext_vector_type(16)));

__device__ __forceinline__ u16 f2b(float x) {
    unsigned int u = __float_as_uint(x);
    return (u16)((u + 0x7FFFu + ((u >> 16) & 1u)) >> 16);
}
__device__ __forceinline__ float b2f(u16 x) {
    return __uint_as_float(((unsigned int)x) << 16);
}

// async global->LDS, 16B per lane; LDS dest = base + lane*16 (linear)
__device__ __forceinline__ void gll16(const u16* g, char* l) {
    __builtin_amdgcn_global_load_lds(
        (const __attribute__((address_space(1))) void*)g,
        (__attribute__((address_space(3))) void*)l, 16, 0, 0);
}

// ---------------------------------------------------------------------------
// ALL packing in one launch (grid 4096) — identical to round 15.
// ---------------------------------------------------------------------------
__global__ __launch_bounds__(256) void pack_all(
    const float* __restrict__ w3, const float* __restrict__ w1,
    const float* __restrict__ wtf,
    const float* __restrict__ wp, const float* __restrict__ wr,
    const float* __restrict__ in4, const float* __restrict__ in5,
    u16* __restrict__ A3f, u16* __restrict__ A1f, u16* __restrict__ Wtff,
    u16* __restrict__ Wefff, u16* __restrict__ c4t, u16* __restrict__ c5f,
    float* __restrict__ pool4, float* __restrict__ pool5)
{
    __shared__ float sT[16448];
    const int t = threadIdx.x;
    const int blk = blockIdx.x;

    if (blk < 3072) {
        int i = blk * 256 + t;
        if (i < 589824) {
            int j  = i & 7;
            int l  = (i >> 3) & 63;
            int ks = (i >> 9) & 15;
            int ot = (i >> 13) & 7;
            int tap = i >> 16;
            int oc = ot * 32 + (l & 31);
            int c  = ks * 16 + ((l >> 5) << 3) + j;
            A3f[i] = f2b(w3[((size_t)oc * 256 + c) * 9 + tap]);
        } else if (i < 720896) {
            int i2 = i - 589824;
            int j  = i2 & 7;
            int l  = (i2 >> 3) & 63;
            int ks = (i2 >> 9) & 31;
            int ot = i2 >> 14;
            int oc = ot * 32 + (l & 31);
            int c  = ks * 16 + ((l >> 5) << 3) + j;
            A1f[i2] = f2b(w1[(size_t)oc * 512 + c]);
        } else {
            int i3 = i - 720896;
            int j  = i3 & 7;
            int l  = (i3 >> 3) & 63;
            int ks = (i3 >> 9) & 15;
            int ot = i3 >> 13;
            int oc = ot * 32 + (l & 31);
            int c  = ks * 16 + ((l >> 5) << 3) + j;
            Wtff[i3] = f2b(wtf[(size_t)oc * 256 + c]);
        }
    } else if (blk < 3328) {
        const int oc = blk - 3072, c = t;
        float s = 0.f;
        for (int f = 0; f < 128; ++f)
            s += wp[oc * 128 + f] * wr[f * 256 + c];
        int ot = oc >> 5;
        int lf = (oc & 31) + (((c >> 3) & 1) << 5);
        int ks = c >> 4;
        int j  = c & 7;
        Wefff[(((size_t)ot * 16 + ks) * 64 + lf) * 8 + j] = f2b(s);
    } else {
        const int id = blk - 3328;            // 0..767
        const int b = id / 96, x = id % 96;
        if (x < 64) {
            const int h = x;
            const int w = t & 63, cg = t >> 6;
            for (int i = 0; i < 64; ++i) {
                int c = cg * 64 + i;
                sT[w * 257 + c] = in4[(((size_t)b * 256 + c) * 64 + h) * 64 + w];
            }
            __syncthreads();
            for (int i = 0; i < 16; ++i) {
                int ww = cg * 16 + i;
                int c0 = (t & 63) * 4;
                ushort4 v;
                v.x = f2b(sT[ww * 257 + c0]);
                v.y = f2b(sT[ww * 257 + c0 + 1]);
                v.z = f2b(sT[ww * 257 + c0 + 2]);
                v.w = f2b(sT[ww * 257 + c0 + 3]);
                *(ushort4*)&c4t[(((size_t)b * 66 + h + 1) * 72 + ww + 1) * 256 + c0] = v;
            }
            {
                const int c = t;
                float cs[3];
                #pragma unroll
                for (int j = 0; j < 3; ++j) {
                    const int w0 = (j * 64) / 3, w1 = ((j + 1) * 64 + 2) / 3;
                    float s = 0.f;
                    for (int w2 = w0; w2 < w1; ++w2) s += sT[w2 * 257 + c];
                    cs[j] = s;
                }
                #pragma unroll
                for (int i = 0; i < 3; ++i) {
                    const int h0 = (i * 64) / 3, h1 = ((i + 1) * 64 + 2) / 3;
                    if (h >= h0 && h < h1) {
                        #pragma unroll
                        for (int j = 0; j < 3; ++j)
                            atomicAdd(&pool4[((size_t)b * 256 + c) * 9 + i * 3 + j], cs[j]);
                    }
                }
            }
        } else {
            const int h2 = x - 64;
            const int w = t & 31, cg = t >> 5;
            for (int i = 0; i < 64; ++i) {
                int c = cg * 64 + i;
                sT[w * 513 + c] = in5[(((size_t)b * 512 + c) * 32 + h2) * 32 + w];
            }
            __syncthreads();
            u16* dstb = c5f + (size_t)(b * 32 + h2) * 32768;
            for (int i = 0; i < 32; ++i) {
                int id2 = i * 256 + t;               // 0..8191
                int j0 = (id2 & 1) * 4;
                int l  = (id2 >> 1) & 63;
                int ks = (id2 >> 7) & 31;
                int n  = (id2 >> 12) & 1;
                int ch = ks * 16 + ((l >> 5) << 3) + j0;
                int w2 = (n * 32 + (l & 31)) >> 1;
                ushort4 v;
                v.x = f2b(sT[w2 * 513 + ch]);
                v.y = f2b(sT[w2 * 513 + ch + 1]);
                v.z = f2b(sT[w2 * 513 + ch + 2]);
                v.w = f2b(sT[w2 * 513 + ch + 3]);
                *(ushort4*)&dstb[id2 * 4] = v;
            }
            #pragma unroll
            for (int half = 0; half < 2; ++half) {
                const int cc = half * 256 + t;
                float cs[3];
                #pragma unroll
                for (int j = 0; j < 3; ++j) {
                    const int w0 = (j * 64) / 3, w1 = ((j + 1) * 64 + 2) / 3;
                    float s = 0.f;
                    for (int w2 = w0; w2 < w1; ++w2) s += sT[(w2 >> 1) * 513 + cc];
                    cs[j] = s;
                }
                #pragma unroll
                for (int i = 0; i < 3; ++i) {
                    const int h0 = (i * 64) / 3, h1 = ((i + 1) * 64 + 2) / 3;
                    const int wt = (int)(2 * h2 >= h0 && 2 * h2 < h1)
                                 + (int)(2 * h2 + 1 >= h0 && 2 * h2 + 1 < h1);
                    if (wt) {
                        const float fw = (float)wt;
                        #pragma unroll
                        for (int j = 0; j < 3; ++j)
                            atomicAdd(&pool5[((size_t)b * 512 + cc) * 9 + i * 3 + j], fw * cs[j]);
                    }
                }
            }
        }
    }
}

// ---------------------------------------------------------------------------
// Fully fused MFMA kernel, 2 BLOCKS/CU (independent barrier domains).
// Per block: one output row h of one image b; tile 256 oc x 64 px.
// block 512 = 8 waves = 4 oc-groups x 2 px-halves; each wave 64oc x 32px.
//  phase 1: fused[256oc][64px] -> LDS bf16; phase 2: [Wtf;Weff] @ fused.
// LDS 57344 B: halo dbuf 2 x (3 rows x 72 px x 128 B) = 55296, unioned with
// 32 KB phase-2 tile; lsum/lsq at [55296, 57344).
// grid 512 (XCD-swizzled: image = lin&7).
// ---------------------------------------------------------------------------
__global__ __launch_bounds__(512, 4) void fuse_all(
    const u16* __restrict__ c4t, const u16* __restrict__ c5f,
    const u16* __restrict__ A3f, const u16* __restrict__ A1f,
    const u16* __restrict__ Wtff, const u16* __restrict__ Wefff,
    u16* __restrict__ yb, u16* __restrict__ outb, float* __restrict__ sums)
{
    extern __shared__ char smem[];                  // 57344 B
    float* lsum = (float*)(smem + 55296);           // 256
    float* lsq  = lsum + 256;                       // 256

    const int t   = threadIdx.x;
    const int lin = blockIdx.x;
    const int d   = ((lin & 7) << 6) + (lin >> 3);  // XCD-swizzle: image/XCD
    const int b   = d >> 6;
    const int h   = d & 63;

    const int l   = t & 63;
    const int w8  = t >> 6;                         // 0..7
    const int og  = w8 & 3;                         // oc group (64 oc)
    const int pxh = w8 >> 2;                        // px half (32 px)
    const int lc  = l & 31;
    const int lg  = l >> 5;

    const int otb = og * 2;                         // 32-oc tile base
    const int gseg = (l & 7) ^ (l >> 3);            // source swizzle

    if (t < 256) { lsum[t] = 0.f; lsq[t] = 0.f; }

    floatx16 acc[2];
    #pragma unroll
    for (int m = 0; m < 2; ++m)
        #pragma unroll
        for (int r = 0; r < 16; ++r)
            acc[m][r] = 0.f;

    // rolling A prefetch buffer: 9 taps x 2 m (72 VGPRs)
    bf16x8 areg[9][2];
    #pragma unroll
    for (int tap = 0; tap < 9; ++tap)
        #pragma unroll
        for (int m = 0; m < 2; ++m)
            areg[tap][m] = *(const bf16x8*)(A3f + ((((size_t)tap * 8 + otb + m) * 16 + 0) * 64 + l) * 8);

    // ---------- prologue: stage chunk 0 into buf0 (3 rows x 72 px) ----------
    for (int q = w8; q < 27; q += 8) {
        const int r  = q / 9;
        const int cq = (q - r * 9) * 8;
        const u16* gp = c4t + ((((size_t)b * 66 + h + r) * 72 + cq + (l >> 3)) << 8)
                      + gseg * 8;
        gll16(gp, smem + (r * 72 + cq) * 128);
    }
    __syncthreads();

    // ------------------- phase 1a: conv3x3, 4 chunks of 64 ch -------------------
    for (int c0 = 0; c0 < 256; c0 += 64) {
        char* bufc = smem + ((c0 >> 6) & 1) * 27648;
        if (c0 < 192) {
            char* bufn = smem + (((c0 >> 6) + 1) & 1) * 27648;
            for (int q = w8; q < 27; q += 8) {
                const int r  = q / 9;
                const int cq = (q - r * 9) * 8;
                const u16* gp = c4t + ((((size_t)b * 66 + h + r) * 72 + cq + (l >> 3)) << 8)
                              + c0 + 64 + gseg * 8;
                gll16(gp, bufn + (r * 72 + cq) * 128);
            }
        }

        const int ksb = c0 >> 4;
        #pragma unroll
        for (int kst = 0; kst < 4; ++kst) {
            const int ksgN = (kst < 3) ? (ksb + kst + 1)
                                       : ((c0 < 192) ? ksb + 4 : 0);
            #pragma unroll
            for (int ky = 0; ky < 3; ++ky) {
                #pragma unroll
                for (int kx = 0; kx < 3; ++kx) {
                    const int tap = ky * 3 + kx;
                    const int pix = ky * 72 + pxh * 32 + lc + kx;
                    const int seg = (kst * 2 + lg) ^ (pix & 7);
                    bf16x8 bb = *(const bf16x8*)(bufc + pix * 128 + (seg << 4));
                    #pragma unroll
                    for (int m = 0; m < 2; ++m)
                        acc[m] = __builtin_amdgcn_mfma_f32_32x32x16_bf16(
                            areg[tap][m], bb, acc[m], 0, 0, 0);
                    #pragma unroll
                    for (int m = 0; m < 2; ++m)
                        areg[tap][m] = *(const bf16x8*)(A3f + ((((size_t)tap * 8 + otb + m) * 16 + ksgN) * 64 + l) * 8);
                }
            }
        }
        __syncthreads();
    }

    // ------------------- phase 1b: conv1x1 over c5_up (K=512) -------------------
    const u16* c5b = c5f + (size_t)(b * 32 + (h >> 1)) * 32768;
    {
        bf16x8 a1[2][2], b1[2];
        #pragma unroll
        for (int m = 0; m < 2; ++m)
            a1[0][m] = *(const bf16x8*)(A1f + ((((size_t)otb + m) * 32 + 0) * 64 + l) * 8);
        b1[0] = *(const bf16x8*)(c5b + (((size_t)pxh * 32 + 0) * 64 + l) * 8);
        #pragma unroll
        for (int ks = 0; ks < 32; ++ks) {
            const int cur = ks & 1, nxt = cur ^ 1;
            if (ks < 31) {
                #pragma unroll
                for (int m = 0; m < 2; ++m)
                    a1[nxt][m] = *(const bf16x8*)(A1f + ((((size_t)otb + m) * 32 + ks + 1) * 64 + l) * 8);
                b1[nxt] = *(const bf16x8*)(c5b + (((size_t)pxh * 32 + ks + 1) * 64 + l) * 8);
            }
            #pragma unroll
            for (int m = 0; m < 2; ++m)
                acc[m] = __builtin_amdgcn_mfma_f32_32x32x16_bf16(
                    a1[cur][m], b1[cur], acc[m], 0, 0, 0);
        }
    }

    // ---- write fused tile to LDS (bf16, [px64][ch256], slot-XOR swizzle) ----
    __syncthreads();                                // halo dead; reuse region
    {
        const int px = pxh * 32 + lc;
        #pragma unroll
        for (int m = 0; m < 2; ++m) {
            #pragma unroll
            for (int rq = 0; rq < 4; ++rq) {
                const int oc = og * 64 + m * 32 + rq * 8 + lg * 4;
                const int slot = oc >> 3;           // 0..31
                ushort4 v;
                v.x = f2b(acc[m][rq * 4 + 0]);
                v.y = f2b(acc[m][rq * 4 + 1]);
                v.z = f2b(acc[m][rq * 4 + 2]);
                v.w = f2b(acc[m][rq * 4 + 3]);
                *(ushort4*)(smem + px * 512 + ((slot ^ (px & 31)) << 4) + (oc & 7) * 2) = v;
            }
        }
    }
    __syncthreads();

    // ------------------- phase 2: [Wtf; Weff] @ fused (K=256) -------------------
    const bool isY = (w8 < 4);
    const u16* Wf  = isY ? Wtff : Wefff;
    u16* dst       = isY ? yb : outb;
    const int ot2  = (w8 & 3) * 2;                  // 32-row tile base

    floatx16 a2[2][2];
    #pragma unroll
    for (int m = 0; m < 2; ++m)
        #pragma unroll
        for (int n = 0; n < 2; ++n)
            #pragma unroll
            for (int r = 0; r < 16; ++r)
                a2[m][n][r] = 0.f;

    {
        bf16x8 wreg[2][2];
        #pragma unroll
        for (int m = 0; m < 2; ++m)
            wreg[0][m] = *(const bf16x8*)(Wf + ((((size_t)ot2 + m) * 16 + 0) * 64 + l) * 8);

        #pragma unroll
        for (int ks = 0; ks < 16; ++ks) {
            const int cur = ks & 1, nxt = cur ^ 1;
            if (ks < 15) {
                #pragma unroll
                for (int m = 0; m < 2; ++m)
                    wreg[nxt][m] = *(const bf16x8*)(Wf + ((((size_t)ot2 + m) * 16 + ks + 1) * 64 + l) * 8);
            }
            bf16x8 bb[2];
            #pragma unroll
            for (int n = 0; n < 2; ++n) {
                const int px = n * 32 + lc;
                const int slot = ks * 2 + lg;
                bb[n] = *(const bf16x8*)(smem + px * 512 + ((slot ^ (px & 31)) << 4));
            }
            #pragma unroll
            for (int m = 0; m < 2; ++m)
                #pragma unroll
                for (int n = 0; n < 2; ++n)
                    a2[m][n] = __builtin_amdgcn_mfma_f32_32x32x16_bf16(
                        wreg[cur][m], bb[n], a2[m][n], 0, 0, 0);
        }
    }

    // epilogue: bf16 NHWC
    #pragma unroll
    for (int n = 0; n < 2; ++n) {
        const int wcol = n * 32 + lc;
        const size_t gp = (((size_t)b * 64 + h) * 64 + wcol) * 256;
        #pragma unroll
        for (int m = 0; m < 2; ++m) {
            #pragma unroll
            for (int rq = 0; rq < 4; ++rq) {
                const int ocl = (w8 & 3) * 64 + m * 32 + rq * 8 + lg * 4;
                ushort4 v;
                v.x = f2b(a2[m][n][rq * 4 + 0]);
                v.y = f2b(a2[m][n][rq * 4 + 1]);
                v.z = f2b(a2[m][n][rq * 4 + 2]);
                v.w = f2b(a2[m][n][rq * 4 + 3]);
                *(ushort4*)&dst[gp + ocl] = v;
            }
        }
    }

    if (isY) {
        #pragma unroll
        for (int m = 0; m < 2; ++m) {
            #pragma unroll
            for (int r = 0; r < 16; ++r) {
                float s = 0.f, q = 0.f;
                #pragma unroll
                for (int n = 0; n < 2; ++n) {
                    float v = a2[m][n][r];
                    s += v; q += v * v;
                }
                #pragma unroll
                for (int off = 1; off < 32; off <<= 1) {
                    s += __shfl_xor(s, off);
                    q += __shfl_xor(q, off);
                }
                if (lc == 0) {
                    const int ocl = (w8 & 3) * 64 + m * 32 + (r & 3) + 8 * (r >> 2) + 4 * lg;
                    atomicAdd(&lsum[ocl], s);
                    atomicAdd(&lsq[ocl], q);
                }
            }
        }
    }

    __syncthreads();
    if (t < 256) {
        atomicAdd(&sums[t], lsum[t]);
        atomicAdd(&sums[256 + t], lsq[t]);
    }
}

// ---------------------------------------------------------------------------
// sim + gating MLP + softmax; pools are SUMS -> scale by 1/area^2.
// ---------------------------------------------------------------------------
__global__ __launch_bounds__(64) void sim_mlp(
    const float* __restrict__ pool4, const float* __restrict__ pool5,
    const float* __restrict__ w4, const float* __restrict__ w5,
    const float* __restrict__ kgw1, const float* __restrict__ kgb1,
    const float* __restrict__ kgw2, const float* __restrict__ kgb2,
    const float* __restrict__ mask, float* __restrict__ kers)
{
    const int r = blockIdx.x, b = blockIdx.y, m = threadIdx.x;
    float p4 = 0.f, p5 = 0.f;
    for (int c = 0; c < C4_; ++c)
        p4 += w4[(size_t)m * C4_ + c] * pool4[((size_t)b * C4_ + c) * 9 + r];
    for (int c = 0; c < C5_; ++c)
        p5 += w5[(size_t)m * C5_ + c] * pool5[((size_t)b * C5_ + c) * 9 + r];
    float v = p4 * p5;
    #pragma unroll
    for (int off = 32; off; off >>= 1) v += __shfl_down(v, off);
    if (m == 0) {
        const int ri = r / 3, rj = r % 3;
        const int h0 = (ri * 64) / 3, h1 = ((ri + 1) * 64 + 2) / 3;
        const int w0 = (rj * 64) / 3, w1 = ((rj + 1) * 64 + 2) / 3;
        const float inv = 1.f / (float)((h1 - h0) * (w1 - w0));
        v *= inv * inv;
        float g = v * (1.f / (1.f + __expf(-mask[r])));
        float hb[16];
        #pragma unroll
        for (int j = 0; j < 16; ++j) hb[j] = fmaxf(g * kgw1[j] + kgb1[j], 0.f);
        float lg[9], mx = -1e30f;
        #pragma unroll
        for (int k = 0; k < 9; ++k) {
            float s = kgb2[k];
            #pragma unroll
            for (int j = 0; j < 16; ++j) s += kgw2[k * 16 + j] * hb[j];
            lg[k] = s;
            mx = fmaxf(mx, s);
        }
        float den = 0.f;
        #pragma unroll
        for (int k = 0; k < 9; ++k) { lg[k] = __expf(lg[k] - mx); den += lg[k]; }
        float inv2 = 1.f / den;
        #pragma unroll
        for (int k = 0; k < 9; ++k)
            kers[((size_t)b * 9 + r) * 9 + k] = lg[k] * inv2;
    }
}

// ---------------------------------------------------------------------------
// Dynamic 3x3 per-region conv, fused BN (derived in-block) + SiLU.
// 1-D grid 4096, XCD-swizzled (image -> XCD).
// ---------------------------------------------------------------------------
__global__ __launch_bounds__(256) void dynconv_bn(const u16* __restrict__ yb,
                                                  const u16* __restrict__ outb,
                                                  const float* __restrict__ sums,
                                                  const float* __restrict__ gamma,
                                                  const float* __restrict__ beta,
                                                  const float* __restrict__ kers,
                                                  float* __restrict__ out)
{
    __shared__ float sX[4][10][66];
    __shared__ float sK[81];
    __shared__ float sAB[8];
    const int t = threadIdx.x;
    const int lin = blockIdx.x;
    const int dd  = ((lin & 7) << 9) | (lin >> 3);   // image -> XCD
    const int b   = dd >> 9;
    const int r0  = ((dd >> 6) & 7) * 8;
    const int cg  = dd & 63;
    const int ch = t >> 6, w = t & 63;
    const int c = cg * 4 + ch;

    if (t < 4) {
        const int cc = cg * 4 + t;
        const float n = (float)(B_ * HW_);
        float mu  = sums[cc] / n;
        float var = sums[256 + cc] / n - mu * mu;
        float a = gamma[cc] * rsqrtf(var + 1e-5f);
        sAB[t]     = a;
        sAB[4 + t] = beta[cc] - mu * a;
    }
    if (t < 81) sK[t] = kers[(size_t)b * 81 + t];
    __syncthreads();

    for (int idx = t; idx < 660; idx += 256) {
        int rr = idx / 66, cl = idx % 66;
        int gh = r0 - 1 + rr, gw = cl - 1;
        float v0 = 0.f, v1 = 0.f, v2 = 0.f, v3 = 0.f;
        if (gh >= 0 && gh < H_ && gw >= 0 && gw < W_) {
            ushort4 u = *(const ushort4*)&yb[((((size_t)b * 64 + gh) * 64 + gw) << 8) + cg * 4];
            float z;
            z = fmaf(sAB[0], b2f(u.x), sAB[4]); v0 = z / (1.f + __expf(-z));
            z = fmaf(sAB[1], b2f(u.y), sAB[5]); v1 = z / (1.f + __expf(-z));
            z = fmaf(sAB[2], b2f(u.z), sAB[6]); v2 = z / (1.f + __expf(-z));
            z = fmaf(sAB[3], b2f(u.w), sAB[7]); v3 = z / (1.f + __expf(-z));
        }
        sX[0][rr][cl] = v0;
        sX[1][rr][cl] = v1;
        sX[2][rr][cl] = v2;
        sX[3][rr][cl] = v3;
    }
    __syncthreads();

    const int rx = (w * 3) >> 6;
    for (int hh = 0; hh < 8; ++hh) {
        int h = r0 + hh;
        int ry = (h * 3) >> 6;
        const float* kp = &sK[(ry * 3 + rx) * 9];
        float acc = 0.f;
        #pragma unroll
        for (int dy = 0; dy < 3; ++dy)
            #pragma unroll
            for (int dx = 0; dx < 3; ++dx)
                acc += kp[dy * 3 + dx] * sX[ch][hh + dy][w + dx];
        acc += b2f(outb[((((size_t)b * 64 + h) * 64 + w) << 8) + c]);
        out[(((size_t)b * 256 + c) * H_ + h) * W_ + w] = acc;
    }
}

// ---------------------------------------------------------------------------
// Launch
// ---------------------------------------------------------------------------
extern "C" void kernel_launch(void* const* d_in, const int* in_sizes, int n_in,
                              void* d_out, int out_size, void* d_ws, size_t ws_size,
                              hipStream_t stream)
{
    const float* c4       = (const float*)d_in[0];
    const float* c5       = (const float*)d_in[1];
    const float* w_to_fuse= (const float*)d_in[2];
    const float* bn_gamma = (const float*)d_in[3];
    const float* bn_beta  = (const float*)d_in[4];
    const float* w_c4_proc= (const float*)d_in[5];
    const float* w_conv1  = (const float*)d_in[6];
    const float* w_reshape= (const float*)d_in[7];
    const float* w_proj   = (const float*)d_in[8];
    const float* w_sim4   = (const float*)d_in[9];
    const float* w_sim5   = (const float*)d_in[10];
    const float* kg_w1    = (const float*)d_in[11];
    const float* kg_b1    = (const float*)d_in[12];
    const float* kg_w2    = (const float*)d_in[13];
    const float* kg_b2    = (const float*)d_in[14];
    const float* mask_raw = (const float*)d_in[15];

    float* out = (float*)d_out;

    // workspace layout (u16 unless noted)
    u16*   yb    = (u16*)d_ws;                         // 8388608
    u16*   outb  = yb + 8388608;                       // 8388608
    u16*   c4t   = outb + 8388608;                     // 9732096 (padded 66x72)
    u16*   c5f   = c4t + 9732096;                      // 8388608 (fragment order)
    u16*   A3f   = c5f + 8388608;                      // 589824
    u16*   A1f   = A3f + 589824;                       // 131072
    u16*   Wtff  = A1f + 131072;                       // 65536
    u16*   Wefff = Wtff + 65536;                       // 65536
    float* pool4 = (float*)(Wefff + 65536);            // 18432 f32 (SUMS)
    float* pool5 = pool4 + 18432;                      // 36864 f32 (SUMS)
    float* sums  = pool5 + 36864;                      // 512
    float* kers  = sums + 512;                         // 648

    hipMemsetAsync(pool4, 0, (size_t)(18432 + 36864 + 512) * sizeof(float), stream);
    hipMemsetAsync(c4t, 0, (size_t)9732096 * sizeof(u16), stream);

    pack_all<<<4096, 256, 0, stream>>>(w_c4_proc, w_conv1, w_to_fuse,
                                       w_proj, w_reshape, c4, c5,
                                       A3f, A1f, Wtff, Wefff, c4t, c5f,
                                       pool4, pool5);

    fuse_all<<<512, 512, 57344, stream>>>(c4t, c5f, A3f, A1f, Wtff, Wefff,
                                          yb, outb, sums);

    sim_mlp<<<dim3(9, 8), 64, 0, stream>>>(pool4, pool5, w_sim4, w_sim5,
                                           kg_w1, kg_b1, kg_w2, kg_b2,
                                           mask_raw, kers);

    dynconv_bn<<<4096, 256, 0, stream>>>(yb, outb, sums,
                                         bn_gamma, bn_beta, kers, out);
}

// Round 17
// 219.250 us; speedup vs baseline: 1.0861x; 1.0861x over previous
//
#include <hip/hip_runtime.h>
#include <cstddef>

// Problem constants
#define B_   8
#define C4_  256
#define C5_  512
#define OC_  256
#define FR_  128
#define H_   64
#define W_   64
#define HW_  4096

typedef unsigned short u16;
typedef __bf16 bf16x8 __attribute__((ext_vector_type(8)));
typedef float floatx16 __attribute__((ext_vector_type(16)));

__device__ __forceinline__ u16 f2b(float x) {
    unsigned int u = __float_as_uint(x);
    return (u16)((u + 0x7FFFu + ((u >> 16) & 1u)) >> 16);
}
__device__ __forceinline__ float b2f(u16 x) {
    return __uint_as_float(((unsigned int)x) << 16);
}

// async global->LDS, 16B per lane; LDS dest = base + lane*16 (linear)
__device__ __forceinline__ void gll16(const u16* g, char* l) {
    __builtin_amdgcn_global_load_lds(
        (const __attribute__((address_space(1))) void*)g,
        (__attribute__((address_space(3))) void*)l, 16, 0, 0);
}

// ---------------------------------------------------------------------------
// ALL packing in one launch (grid 4096).
// ---------------------------------------------------------------------------
__global__ __launch_bounds__(256) void pack_all(
    const float* __restrict__ w3, const float* __restrict__ w1,
    const float* __restrict__ wtf,
    const float* __restrict__ wp, const float* __restrict__ wr,
    const float* __restrict__ in4, const float* __restrict__ in5,
    u16* __restrict__ A3f, u16* __restrict__ A1f, u16* __restrict__ Wtff,
    u16* __restrict__ Wefff, u16* __restrict__ c4t, u16* __restrict__ c5f,
    float* __restrict__ pool4, float* __restrict__ pool5)
{
    __shared__ float sT[16448];
    const int t = threadIdx.x;
    const int blk = blockIdx.x;

    if (blk < 3072) {
        int i = blk * 256 + t;
        if (i < 589824) {
            int j  = i & 7;
            int l  = (i >> 3) & 63;
            int ks = (i >> 9) & 15;
            int ot = (i >> 13) & 7;
            int tap = i >> 16;
            int oc = ot * 32 + (l & 31);
            int c  = ks * 16 + ((l >> 5) << 3) + j;
            A3f[i] = f2b(w3[((size_t)oc * 256 + c) * 9 + tap]);
        } else if (i < 720896) {
            int i2 = i - 589824;
            int j  = i2 & 7;
            int l  = (i2 >> 3) & 63;
            int ks = (i2 >> 9) & 31;
            int ot = i2 >> 14;
            int oc = ot * 32 + (l & 31);
            int c  = ks * 16 + ((l >> 5) << 3) + j;
            A1f[i2] = f2b(w1[(size_t)oc * 512 + c]);
        } else {
            int i3 = i - 720896;
            int j  = i3 & 7;
            int l  = (i3 >> 3) & 63;
            int ks = (i3 >> 9) & 15;
            int ot = i3 >> 13;
            int oc = ot * 32 + (l & 31);
            int c  = ks * 16 + ((l >> 5) << 3) + j;
            Wtff[i3] = f2b(wtf[(size_t)oc * 256 + c]);
        }
    } else if (blk < 3328) {
        const int oc = blk - 3072, c = t;
        float s = 0.f;
        for (int f = 0; f < 128; ++f)
            s += wp[oc * 128 + f] * wr[f * 256 + c];
        int ot = oc >> 5;
        int lf = (oc & 31) + (((c >> 3) & 1) << 5);
        int ks = c >> 4;
        int j  = c & 7;
        Wefff[(((size_t)ot * 16 + ks) * 64 + lf) * 8 + j] = f2b(s);
    } else {
        const int id = blk - 3328;            // 0..767
        const int b = id / 96, x = id % 96;
        if (x < 64) {
            const int h = x;
            const int w = t & 63, cg = t >> 6;
            for (int i = 0; i < 64; ++i) {
                int c = cg * 64 + i;
                sT[w * 257 + c] = in4[(((size_t)b * 256 + c) * 64 + h) * 64 + w];
            }
            __syncthreads();
            for (int i = 0; i < 16; ++i) {
                int ww = cg * 16 + i;
                int c0 = (t & 63) * 4;
                ushort4 v;
                v.x = f2b(sT[ww * 257 + c0]);
                v.y = f2b(sT[ww * 257 + c0 + 1]);
                v.z = f2b(sT[ww * 257 + c0 + 2]);
                v.w = f2b(sT[ww * 257 + c0 + 3]);
                *(ushort4*)&c4t[(((size_t)b * 66 + h + 1) * 72 + ww + 1) * 256 + c0] = v;
            }
            {
                const int c = t;
                float cs[3];
                #pragma unroll
                for (int j = 0; j < 3; ++j) {
                    const int w0 = (j * 64) / 3, w1 = ((j + 1) * 64 + 2) / 3;
                    float s = 0.f;
                    for (int w2 = w0; w2 < w1; ++w2) s += sT[w2 * 257 + c];
                    cs[j] = s;
                }
                #pragma unroll
                for (int i = 0; i < 3; ++i) {
                    const int h0 = (i * 64) / 3, h1 = ((i + 1) * 64 + 2) / 3;
                    if (h >= h0 && h < h1) {
                        #pragma unroll
                        for (int j = 0; j < 3; ++j)
                            atomicAdd(&pool4[((size_t)b * 256 + c) * 9 + i * 3 + j], cs[j]);
                    }
                }
            }
        } else {
            const int h2 = x - 64;
            const int w = t & 31, cg = t >> 5;
            for (int i = 0; i < 64; ++i) {
                int c = cg * 64 + i;
                sT[w * 513 + c] = in5[(((size_t)b * 512 + c) * 32 + h2) * 32 + w];
            }
            __syncthreads();
            u16* dstb = c5f + (size_t)(b * 32 + h2) * 32768;
            for (int i = 0; i < 32; ++i) {
                int id2 = i * 256 + t;               // 0..8191
                int j0 = (id2 & 1) * 4;
                int l  = (id2 >> 1) & 63;
                int ks = (id2 >> 7) & 31;
                int n  = (id2 >> 12) & 1;
                int ch = ks * 16 + ((l >> 5) << 3) + j0;
                int w2 = (n * 32 + (l & 31)) >> 1;
                ushort4 v;
                v.x = f2b(sT[w2 * 513 + ch]);
                v.y = f2b(sT[w2 * 513 + ch + 1]);
                v.z = f2b(sT[w2 * 513 + ch + 2]);
                v.w = f2b(sT[w2 * 513 + ch + 3]);
                *(ushort4*)&dstb[id2 * 4] = v;
            }
            #pragma unroll
            for (int half = 0; half < 2; ++half) {
                const int cc = half * 256 + t;
                float cs[3];
                #pragma unroll
                for (int j = 0; j < 3; ++j) {
                    const int w0 = (j * 64) / 3, w1 = ((j + 1) * 64 + 2) / 3;
                    float s = 0.f;
                    for (int w2 = w0; w2 < w1; ++w2) s += sT[(w2 >> 1) * 513 + cc];
                    cs[j] = s;
                }
                #pragma unroll
                for (int i = 0; i < 3; ++i) {
                    const int h0 = (i * 64) / 3, h1 = ((i + 1) * 64 + 2) / 3;
                    const int wt = (int)(2 * h2 >= h0 && 2 * h2 < h1)
                                 + (int)(2 * h2 + 1 >= h0 && 2 * h2 + 1 < h1);
                    if (wt) {
                        const float fw = (float)wt;
                        #pragma unroll
                        for (int j = 0; j < 3; ++j)
                            atomicAdd(&pool5[((size_t)b * 512 + cc) * 9 + i * 3 + j], fw * cs[j]);
                    }
                }
            }
        }
    }
}

// ---------------------------------------------------------------------------
// Fully fused MFMA kernel; DOUBLE-BUFFERED issue-early halo staging.
// grid 256 (XCD-swizzled, 1 block/CU), block 512 = 8 waves.
// LDS: 2 x 36864 halo dbuf (phase-2 tile unions over it) + 2KB sums = 75776.
// ---------------------------------------------------------------------------
__global__ __launch_bounds__(512, 1) void fuse_all(
    const u16* __restrict__ c4t, const u16* __restrict__ c5f,
    const u16* __restrict__ A3f, const u16* __restrict__ A1f,
    const u16* __restrict__ Wtff, const u16* __restrict__ Wefff,
    u16* __restrict__ yb, u16* __restrict__ outb, float* __restrict__ sums)
{
    extern __shared__ char smem[];                  // 75776 B
    float* lsum = (float*)(smem + 73728);           // 256
    float* lsq  = lsum + 256;                       // 256

    const int t   = threadIdx.x;
    const int lin = blockIdx.x;
    const int d   = ((lin & 7) << 5) + (lin >> 3);  // XCD-swizzle: image/XCD
    const int b   = d >> 5;
    const int rp  = d & 31;
    const int h0  = rp * 2;

    const int l   = t & 63;
    const int w8  = t >> 6;                         // 0..7
    const int og  = w8 >> 1;                        // oc group (64 oc)
    const int pg  = w8 & 1;                         // px row of pair
    const int lc  = l & 31;
    const int lg  = l >> 5;

    const int ocb = og * 64;
    const int otb = og * 2;                         // 32-oc tile base
    const int gseg = (l & 7) ^ (l >> 3);            // source swizzle

    if (t < 256) { lsum[t] = 0.f; lsq[t] = 0.f; }

    floatx16 acc[2][2];
    #pragma unroll
    for (int m = 0; m < 2; ++m)
        #pragma unroll
        for (int n = 0; n < 2; ++n)
            #pragma unroll
            for (int r = 0; r < 16; ++r)
                acc[m][n][r] = 0.f;

    // rolling A prefetch buffer: 9 taps x 2 m (72 VGPRs)
    bf16x8 areg[9][2];
    #pragma unroll
    for (int tap = 0; tap < 9; ++tap)
        #pragma unroll
        for (int m = 0; m < 2; ++m)
            areg[tap][m] = *(const bf16x8*)(A3f + ((((size_t)tap * 8 + otb + m) * 16 + 0) * 64 + l) * 8);

    // ---------- prologue: stage chunk 0 into buf0 ----------
    for (int q = w8; q < 36; q += 8) {
        const int r  = q / 9;
        const int cq = (q - r * 9) * 8;
        const u16* gp = c4t + ((((size_t)b * 66 + h0 + r) * 72 + cq + (l >> 3)) << 8)
                      + gseg * 8;
        gll16(gp, smem + (r * 72 + cq) * 128);
    }
    __syncthreads();

    // ------------------- phase 1a: conv3x3, 4 chunks of 64 ch -------------------
    for (int c0 = 0; c0 < 256; c0 += 64) {
        char* bufc = smem + ((c0 >> 6) & 1) * 36864;
        // issue-early: stage chunk c0+64 into the OTHER buffer (no wait)
        if (c0 < 192) {
            char* bufn = smem + (((c0 >> 6) + 1) & 1) * 36864;
            for (int q = w8; q < 36; q += 8) {
                const int r  = q / 9;
                const int cq = (q - r * 9) * 8;
                const u16* gp = c4t + ((((size_t)b * 66 + h0 + r) * 72 + cq + (l >> 3)) << 8)
                              + c0 + 64 + gseg * 8;
                gll16(gp, bufn + (r * 72 + cq) * 128);
            }
        }

        const int ksb = c0 >> 4;
        #pragma unroll
        for (int kst = 0; kst < 4; ++kst) {
            const int ksgN = (kst < 3) ? (ksb + kst + 1)
                                       : ((c0 < 192) ? ksb + 4 : 0);
            #pragma unroll
            for (int ky = 0; ky < 3; ++ky) {
                #pragma unroll
                for (int kx = 0; kx < 3; ++kx) {
                    const int tap = ky * 3 + kx;
                    bf16x8 bb[2];
                    #pragma unroll
                    for (int n = 0; n < 2; ++n) {
                        const int pix = (pg + ky) * 72 + n * 32 + lc + kx;
                        const int seg = (kst * 2 + lg) ^ (pix & 7);
                        bb[n] = *(const bf16x8*)(bufc + pix * 128 + (seg << 4));
                    }
                    #pragma unroll
                    for (int m = 0; m < 2; ++m)
                        #pragma unroll
                        for (int n = 0; n < 2; ++n)
                            acc[m][n] = __builtin_amdgcn_mfma_f32_32x32x16_bf16(
                                areg[tap][m], bb[n], acc[m][n], 0, 0, 0);
                    #pragma unroll
                    for (int m = 0; m < 2; ++m)
                        areg[tap][m] = *(const bf16x8*)(A3f + ((((size_t)tap * 8 + otb + m) * 16 + ksgN) * 64 + l) * 8);
                }
            }
        }
        __syncthreads();    // next chunk staged (issued a full chunk ago)
    }

    // ------------------- phase 1b: conv1x1 over c5_up (K=512) -------------------
    const u16* c5b = c5f + (size_t)(b * 32 + rp) * 32768;
    {
        bf16x8 a1[2][2], b1[2][2];
        #pragma unroll
        for (int m = 0; m < 2; ++m) {
            a1[0][m] = *(const bf16x8*)(A1f + ((((size_t)otb + m) * 32 + 0) * 64 + l) * 8);
            b1[0][m] = *(const bf16x8*)(c5b + (((size_t)m * 32 + 0) * 64 + l) * 8);
        }
        #pragma unroll
        for (int ks = 0; ks < 32; ++ks) {
            const int cur = ks & 1, nxt = cur ^ 1;
            if (ks < 31) {
                #pragma unroll
                for (int m = 0; m < 2; ++m) {
                    a1[nxt][m] = *(const bf16x8*)(A1f + ((((size_t)otb + m) * 32 + ks + 1) * 64 + l) * 8);
                    b1[nxt][m] = *(const bf16x8*)(c5b + (((size_t)m * 32 + ks + 1) * 64 + l) * 8);
                }
            }
            #pragma unroll
            for (int m = 0; m < 2; ++m)
                #pragma unroll
                for (int n = 0; n < 2; ++n)
                    acc[m][n] = __builtin_amdgcn_mfma_f32_32x32x16_bf16(
                        a1[cur][m], b1[cur][n], acc[m][n], 0, 0, 0);
        }
    }

    // ---- write fused tile to LDS (bf16, [px128][ch256], slot-XOR swizzle) ----
    __syncthreads();                                // halo dead; reuse region
    #pragma unroll
    for (int n = 0; n < 2; ++n) {
        const int px = pg * 64 + n * 32 + lc;
        #pragma unroll
        for (int m = 0; m < 2; ++m) {
            #pragma unroll
            for (int rq = 0; rq < 4; ++rq) {
                const int oc = ocb + m * 32 + rq * 8 + lg * 4;
                const int slot = oc >> 3;           // 0..31
                ushort4 v;
                v.x = f2b(acc[m][n][rq * 4 + 0]);
                v.y = f2b(acc[m][n][rq * 4 + 1]);
                v.z = f2b(acc[m][n][rq * 4 + 2]);
                v.w = f2b(acc[m][n][rq * 4 + 3]);
                *(ushort4*)(smem + px * 512 + ((slot ^ (px & 31)) << 4) + (oc & 7) * 2) = v;
            }
        }
    }
    __syncthreads();

    // ------------------- phase 2: [Wtf; Weff] @ fused (K=256) -------------------
    const bool isY = (w8 < 4);
    const u16* Wf  = isY ? Wtff : Wefff;
    u16* dst       = isY ? yb : outb;
    const int ot2  = (w8 & 3) * 2;                  // 32-row tile base

    #pragma unroll
    for (int ph = 0; ph < 2; ++ph) {
        floatx16 a2[2][2];
        #pragma unroll
        for (int m = 0; m < 2; ++m)
            #pragma unroll
            for (int n = 0; n < 2; ++n)
                #pragma unroll
                for (int r = 0; r < 16; ++r)
                    a2[m][n][r] = 0.f;

        bf16x8 wreg[2][2];
        #pragma unroll
        for (int m = 0; m < 2; ++m)
            wreg[0][m] = *(const bf16x8*)(Wf + ((((size_t)ot2 + m) * 16 + 0) * 64 + l) * 8);

        #pragma unroll
        for (int ks = 0; ks < 16; ++ks) {
            const int cur = ks & 1, nxt = cur ^ 1;
            if (ks < 15) {
                #pragma unroll
                for (int m = 0; m < 2; ++m)
                    wreg[nxt][m] = *(const bf16x8*)(Wf + ((((size_t)ot2 + m) * 16 + ks + 1) * 64 + l) * 8);
            }
            bf16x8 bb[2];
            #pragma unroll
            for (int n = 0; n < 2; ++n) {
                const int px = ph * 64 + n * 32 + lc;
                const int slot = ks * 2 + lg;
                bb[n] = *(const bf16x8*)(smem + px * 512 + ((slot ^ (px & 31)) << 4));
            }
            #pragma unroll
            for (int m = 0; m < 2; ++m)
                #pragma unroll
                for (int n = 0; n < 2; ++n)
                    a2[m][n] = __builtin_amdgcn_mfma_f32_32x32x16_bf16(
                        wreg[cur][m], bb[n], a2[m][n], 0, 0, 0);
        }

        // epilogue: bf16 NHWC
        #pragma unroll
        for (int n = 0; n < 2; ++n) {
            const int px = ph * 64 + n * 32 + lc;
            const int row = px >> 6, wcol = px & 63;
            const size_t gp = (((size_t)b * 64 + h0 + row) * 64 + wcol) * 256;
            #pragma unroll
            for (int m = 0; m < 2; ++m) {
                #pragma unroll
                for (int rq = 0; rq < 4; ++rq) {
                    const int ocl = (w8 & 3) * 64 + m * 32 + rq * 8 + lg * 4;
                    ushort4 v;
                    v.x = f2b(a2[m][n][rq * 4 + 0]);
                    v.y = f2b(a2[m][n][rq * 4 + 1]);
                    v.z = f2b(a2[m][n][rq * 4 + 2]);
                    v.w = f2b(a2[m][n][rq * 4 + 3]);
                    *(ushort4*)&dst[gp + ocl] = v;
                }
            }
        }

        if (isY) {
            #pragma unroll
            for (int m = 0; m < 2; ++m) {
                #pragma unroll
                for (int r = 0; r < 16; ++r) {
                    float s = 0.f, q = 0.f;
                    #pragma unroll
                    for (int n = 0; n < 2; ++n) {
                        float v = a2[m][n][r];
                        s += v; q += v * v;
                    }
                    #pragma unroll
                    for (int off = 1; off < 32; off <<= 1) {
                        s += __shfl_xor(s, off);
                        q += __shfl_xor(q, off);
                    }
                    if (lc == 0) {
                        const int ocl = (w8 & 3) * 64 + m * 32 + (r & 3) + 8 * (r >> 2) + 4 * lg;
                        atomicAdd(&lsum[ocl], s);
                        atomicAdd(&lsq[ocl], q);
                    }
                }
            }
        }
    }

    __syncthreads();
    if (t < 256) {
        atomicAdd(&sums[t], lsum[t]);
        atomicAdd(&sums[256 + t], lsq[t]);
    }
}

// ---------------------------------------------------------------------------
// sim + gating MLP + softmax; pools are SUMS -> scale by 1/area^2.
// ---------------------------------------------------------------------------
__global__ __launch_bounds__(64) void sim_mlp(
    const float* __restrict__ pool4, const float* __restrict__ pool5,
    const float* __restrict__ w4, const float* __restrict__ w5,
    const float* __restrict__ kgw1, const float* __restrict__ kgb1,
    const float* __restrict__ kgw2, const float* __restrict__ kgb2,
    const float* __restrict__ mask, float* __restrict__ kers)
{
    const int r = blockIdx.x, b = blockIdx.y, m = threadIdx.x;
    float p4 = 0.f, p5 = 0.f;
    for (int c = 0; c < C4_; ++c)
        p4 += w4[(size_t)m * C4_ + c] * pool4[((size_t)b * C4_ + c) * 9 + r];
    for (int c = 0; c < C5_; ++c)
        p5 += w5[(size_t)m * C5_ + c] * pool5[((size_t)b * C5_ + c) * 9 + r];
    float v = p4 * p5;
    #pragma unroll
    for (int off = 32; off; off >>= 1) v += __shfl_down(v, off);
    if (m == 0) {
        const int ri = r / 3, rj = r % 3;
        const int h0 = (ri * 64) / 3, h1 = ((ri + 1) * 64 + 2) / 3;
        const int w0 = (rj * 64) / 3, w1 = ((rj + 1) * 64 + 2) / 3;
        const float inv = 1.f / (float)((h1 - h0) * (w1 - w0));
        v *= inv * inv;
        float g = v * (1.f / (1.f + __expf(-mask[r])));
        float hb[16];
        #pragma unroll
        for (int j = 0; j < 16; ++j) hb[j] = fmaxf(g * kgw1[j] + kgb1[j], 0.f);
        float lg[9], mx = -1e30f;
        #pragma unroll
        for (int k = 0; k < 9; ++k) {
            float s = kgb2[k];
            #pragma unroll
            for (int j = 0; j < 16; ++j) s += kgw2[k * 16 + j] * hb[j];
            lg[k] = s;
            mx = fmaxf(mx, s);
        }
        float den = 0.f;
        #pragma unroll
        for (int k = 0; k < 9; ++k) { lg[k] = __expf(lg[k] - mx); den += lg[k]; }
        float inv2 = 1.f / den;
        #pragma unroll
        for (int k = 0; k < 9; ++k)
            kers[((size_t)b * 9 + r) * 9 + k] = lg[k] * inv2;
    }
}

// ---------------------------------------------------------------------------
// Dynamic 3x3 per-region conv, fused BN (derived in-block) + SiLU.
// 1-D grid 4096, XCD-swizzled (image -> XCD).
// ---------------------------------------------------------------------------
__global__ __launch_bounds__(256) void dynconv_bn(const u16* __restrict__ yb,
                                                  const u16* __restrict__ outb,
                                                  const float* __restrict__ sums,
                                                  const float* __restrict__ gamma,
                                                  const float* __restrict__ beta,
                                                  const float* __restrict__ kers,
                                                  float* __restrict__ out)
{
    __shared__ float sX[4][10][66];
    __shared__ float sK[81];
    __shared__ float sAB[8];
    const int t = threadIdx.x;
    const int lin = blockIdx.x;
    const int dd  = ((lin & 7) << 9) | (lin >> 3);   // image -> XCD
    const int b   = dd >> 9;
    const int r0  = ((dd >> 6) & 7) * 8;
    const int cg  = dd & 63;
    const int ch = t >> 6, w = t & 63;
    const int c = cg * 4 + ch;

    if (t < 4) {
        const int cc = cg * 4 + t;
        const float n = (float)(B_ * HW_);
        float mu  = sums[cc] / n;
        float var = sums[256 + cc] / n - mu * mu;
        float a = gamma[cc] * rsqrtf(var + 1e-5f);
        sAB[t]     = a;
        sAB[4 + t] = beta[cc] - mu * a;
    }
    if (t < 81) sK[t] = kers[(size_t)b * 81 + t];
    __syncthreads();

    for (int idx = t; idx < 660; idx += 256) {
        int rr = idx / 66, cl = idx % 66;
        int gh = r0 - 1 + rr, gw = cl - 1;
        float v0 = 0.f, v1 = 0.f, v2 = 0.f, v3 = 0.f;
        if (gh >= 0 && gh < H_ && gw >= 0 && gw < W_) {
            ushort4 u = *(const ushort4*)&yb[((((size_t)b * 64 + gh) * 64 + gw) << 8) + cg * 4];
            float z;
            z = fmaf(sAB[0], b2f(u.x), sAB[4]); v0 = z / (1.f + __expf(-z));
            z = fmaf(sAB[1], b2f(u.y), sAB[5]); v1 = z / (1.f + __expf(-z));
            z = fmaf(sAB[2], b2f(u.z), sAB[6]); v2 = z / (1.f + __expf(-z));
            z = fmaf(sAB[3], b2f(u.w), sAB[7]); v3 = z / (1.f + __expf(-z));
        }
        sX[0][rr][cl] = v0;
        sX[1][rr][cl] = v1;
        sX[2][rr][cl] = v2;
        sX[3][rr][cl] = v3;
    }
    __syncthreads();

    const int rx = (w * 3) >> 6;
    for (int hh = 0; hh < 8; ++hh) {
        int h = r0 + hh;
        int ry = (h * 3) >> 6;
        const float* kp = &sK[(ry * 3 + rx) * 9];
        float acc = 0.f;
        #pragma unroll
        for (int dy = 0; dy < 3; ++dy)
            #pragma unroll
            for (int dx = 0; dx < 3; ++dx)
                acc += kp[dy * 3 + dx] * sX[ch][hh + dy][w + dx];
        acc += b2f(outb[((((size_t)b * 64 + h) * 64 + w) << 8) + c]);
        out[(((size_t)b * 256 + c) * H_ + h) * W_ + w] = acc;
    }
}

// ---------------------------------------------------------------------------
// Launch
// ---------------------------------------------------------------------------
extern "C" void kernel_launch(void* const* d_in, const int* in_sizes, int n_in,
                              void* d_out, int out_size, void* d_ws, size_t ws_size,
                              hipStream_t stream)
{
    const float* c4       = (const float*)d_in[0];
    const float* c5       = (const float*)d_in[1];
    const float* w_to_fuse= (const float*)d_in[2];
    const float* bn_gamma = (const float*)d_in[3];
    const float* bn_beta  = (const float*)d_in[4];
    const float* w_c4_proc= (const float*)d_in[5];
    const float* w_conv1  = (const float*)d_in[6];
    const float* w_reshape= (const float*)d_in[7];
    const float* w_proj   = (const float*)d_in[8];
    const float* w_sim4   = (const float*)d_in[9];
    const float* w_sim5   = (const float*)d_in[10];
    const float* kg_w1    = (const float*)d_in[11];
    const float* kg_b1    = (const float*)d_in[12];
    const float* kg_w2    = (const float*)d_in[13];
    const float* kg_b2    = (const float*)d_in[14];
    const float* mask_raw = (const float*)d_in[15];

    float* out = (float*)d_out;

    // workspace layout (u16 unless noted)
    u16*   yb    = (u16*)d_ws;                         // 8388608
    u16*   outb  = yb + 8388608;                       // 8388608
    u16*   c4t   = outb + 8388608;                     // 9732096 (padded 66x72)
    u16*   c5f   = c4t + 9732096;                      // 8388608 (fragment order)
    u16*   A3f   = c5f + 8388608;                      // 589824
    u16*   A1f   = A3f + 589824;                       // 131072
    u16*   Wtff  = A1f + 131072;                       // 65536
    u16*   Wefff = Wtff + 65536;                       // 65536
    float* pool4 = (float*)(Wefff + 65536);            // 18432 f32 (SUMS)
    float* pool5 = pool4 + 18432;                      // 36864 f32 (SUMS)
    float* sums  = pool5 + 36864;                      // 512
    float* kers  = sums + 512;                         // 648

    hipMemsetAsync(pool4, 0, (size_t)(18432 + 36864 + 512) * sizeof(float), stream);
    hipMemsetAsync(c4t, 0, (size_t)9732096 * sizeof(u16), stream);

    pack_all<<<4096, 256, 0, stream>>>(w_c4_proc, w_conv1, w_to_fuse,
                                       w_proj, w_reshape, c4, c5,
                                       A3f, A1f, Wtff, Wefff, c4t, c5f,
                                       pool4, pool5);

    fuse_all<<<256, 512, 75776, stream>>>(c4t, c5f, A3f, A1f, Wtff, Wefff,
                                          yb, outb, sums);

    sim_mlp<<<dim3(9, 8), 64, 0, stream>>>(pool4, pool5, w_sim4, w_sim5,
                                           kg_w1, kg_b1, kg_w2, kg_b2,
                                           mask_raw, kers);

    dynconv_bn<<<4096, 256, 0, stream>>>(yb, outb, sums,
                                         bn_gamma, bn_beta, kers, out);
}